// Round 12
// baseline (225.703 us; speedup 1.0000x reference)
//
#include <hip/hip_runtime.h>
#include <cstddef>

typedef __attribute__((ext_vector_type(8))) short short8;
typedef __attribute__((ext_vector_type(4))) float f32x4;

#define MFMA16(a, b, c) __builtin_amdgcn_mfma_f32_16x16x32_bf16((a), (b), (c), 0, 0, 0)

__device__ __forceinline__ unsigned short f2bf(float f) {
    unsigned u = __float_as_uint(f);
    u = (u + 0x7fffu + ((u >> 16) & 1u)) >> 16;
    return (unsigned short)u;
}
__device__ __forceinline__ float bf2f(unsigned short s) {
    return __uint_as_float(((unsigned)s) << 16);
}
__device__ __forceinline__ float sigm(float v) { return 1.f / (1.f + __expf(-v)); }
__device__ __forceinline__ float tanh_(float v) {
    float a = fabsf(v);
    float e = __expf(-2.f * a);
    float t = (1.f - e) / (1.f + e);
    return v < 0.f ? -t : t;
}

// ============================================================================
// MEGA v2: 1024 blocks x 768 threads.
//   blocks   0-255 : GRU (R3/R8/R9-proven), waves at s_setprio(3) — the GRU
//                    is latency-bound (serial 120-step chain, issue slots
//                    mostly idle); priority protects its critical path.
//   blocks 256-1023: LDS-FREE rel streamers (R10's 5-lane-group scheme, 0
//                    bank conflicts) at prio 0 — soak leftover issue slots,
//                    write ar + compact 12-bit/chunk mask to workspace.
// R9's failure was issue contention (no prio) + 3.26M bank conflicts from
// the transpose streamer; both are addressed here.
// ============================================================================
__launch_bounds__(768, 3)
__global__ void mega_kernel(const float* __restrict__ x,
                            const float* __restrict__ Wih0, const float* __restrict__ Whh0,
                            const float* __restrict__ bih0, const float* __restrict__ bhh0,
                            const float* __restrict__ Wih1, const float* __restrict__ Whh1,
                            const float* __restrict__ bih1, const float* __restrict__ bhh1,
                            const float* __restrict__ rel, const float* __restrict__ W,
                            float* __restrict__ xhid, float* __restrict__ arw,
                            unsigned short* __restrict__ maskw16) {
    __shared__ __align__(16) unsigned char smem[79744];

    const int tid  = threadIdx.x;
    const int lane = tid & 63;

    if (blockIdx.x >= 256) {
        // ================= REL STREAMER BLOCK (prio 0, LDS-free) ==============
        __builtin_amdgcn_s_setprio(0);
        const int wv = tid >> 6;                       // 0..11
        const int gw = (blockIdx.x - 256) * 12 + wv;   // 0..9215
        const int g5 = lane / 5;                       // pair slot 0..12
        const int r5 = lane - 5 * g5;                  // 0..4
        float w4[4];
#pragma unroll
        for (int j = 0; j < 4; ++j) w4[j] = W[128 + r5 * 4 + j];

        // chunks of 240 floats = 12 pairs (pair = 20 floats of one (row,j)).
        // total floats 83886080 -> 349526 chunks (last partial).
#define LOADG(c, v)                                                              \
    {                                                                            \
        const int off = (c) * 240 + lane * 4;                                    \
        if (off < 83886080) v = *(const f32x4*)(rel + off);                      \
        else { v[0] = 0.f; v[1] = 0.f; v[2] = 0.f; v[3] = 0.f; }                 \
    }
        f32x4 vc, vn;
        LOADG(gw, vc);
        for (int c = gw; c < 349526; c += 9216) {
            if (c + 9216 < 349526) { LOADG(c + 9216, vn); }
            else { vn[0] = 0.f; vn[1] = 0.f; vn[2] = 0.f; vn[3] = 0.f; }

            const float pd = vc[0] * w4[0] + vc[1] * w4[1]
                           + vc[2] * w4[2] + vc[3] * w4[3];
            const float pm = vc[0] + vc[1] + vc[2] + vc[3];
            float sd = pd + __shfl_down(pd, 1);
            sd += __shfl_down(sd, 2);
            sd += __shfl_down(pd, 4);
            float sm = pm + __shfl_down(pm, 1);
            sm += __shfl_down(sm, 2);
            sm += __shfl_down(pm, 4);

            const int p0 = c * 12 + g5;
            if (r5 == 0 && g5 < 12 && p0 < 4194304) arw[p0] = sd;
            const unsigned long long bal =
                __ballot((r5 == 0) && (g5 < 12) && (sm != 0.f));
            if (lane == 0) {
                unsigned m16 = 0;
#pragma unroll
                for (int g = 0; g < 12; ++g)
                    m16 |= ((unsigned)(bal >> (5 * g)) & 1u) << g;
                maskw16[c] = (unsigned short)m16;
            }
            vc = vn;
        }
#undef LOADG
        return;
    }

    // ================= GRU BLOCK (prio 3; R9 verbatim) =======================
    __builtin_amdgcn_s_setprio(3);
    typedef unsigned short ush;
    ush (*h0h)[1024] = (ush (*)[1024])(smem);
    ush (*h0l)[1024] = (ush (*)[1024])(smem + 4096);
    ush (*h1h)[1024] = (ush (*)[1024])(smem + 8192);
    ush (*h1l)[1024] = (ush (*)[1024])(smem + 12288);
    float (*P1)[16][195] = (float (*)[16][195])(smem + 16384);
    short8* axbuf = (short8*)(smem + 41344);

    const int grp  = tid >> 8;
    const int gw_  = (tid >> 6) & 3;
    const int c    = lane & 15;
    const int q    = lane >> 4;
    const int jj   = gw_ * 16 + c;

    for (int i = tid; i < 1024; i += 768) {
        h0h[0][i] = 0; h0l[0][i] = 0; h1h[0][i] = 0; h1l[0][i] = 0;
    }
    {
        const float* xb = x + (size_t)blockIdx.x * 8 * 360;
        for (int f = tid; f < 1920; f += 768) {
            const int t = f >> 5, s = (f >> 2) & 7, qq = f & 3;
            unsigned short Hh[6], Ll[6];
#pragma unroll
            for (int d = 0; d < 6; ++d) {
                const float v = xb[s * 360 + d * 60 + t];
                Hh[d] = f2bf(v); Ll[d] = f2bf(v - bf2f(Hh[d]));
            }
            short8 fr;
#pragma unroll
            for (int e = 0; e < 8; ++e) {
                const int k = qq * 8 + e;
                unsigned short u = 0;
                if (k < 6) u = Hh[k];
                else if (k < 12) u = Ll[k - 6];
                else if (k < 18) u = Hh[k - 12];
                fr[e] = (short)u;
            }
            axbuf[t * 40 + s * 5 + qq] = fr;
        }
    }

    const int ka    = q * 8;
    const int swzA0 = c * 64 + (ka ^ ((c & 7) << 3));
    const int swzA1 = c * 64 + ((32 + ka) ^ ((c & 7) << 3));

    __syncthreads();

    if (grp == 0) {
        short8 Bhh[3][2], Bhl[3][2], Bc[3];
#pragma unroll
        for (int g = 0; g < 3; ++g) {
            const int o = g * 64 + jj;
#pragma unroll
            for (int kt = 0; kt < 2; ++kt) {
                const int k0 = kt * 32 + q * 8;
#pragma unroll
                for (int e = 0; e < 8; ++e) {
                    const float v = Whh0[o * 64 + k0 + e];
                    const unsigned short hi = f2bf(v);
                    Bhh[g][kt][e] = (short)hi; Bhl[g][kt][e] = (short)f2bf(v - bf2f(hi));
                }
            }
#pragma unroll
            for (int e = 0; e < 8; ++e) {
                const int ks = q * 8 + e;
                unsigned short bv = 0;
                if (ks < 6)       bv = f2bf(Wih0[o * 6 + ks]);
                else if (ks < 12) bv = f2bf(Wih0[o * 6 + ks - 6]);
                else if (ks < 18) {
                    const float v = Wih0[o * 6 + ks - 12];
                    const unsigned short hi = f2bf(v);
                    bv = f2bf(v - bf2f(hi));
                }
                Bc[g][e] = (short)bv;
            }
        }
        const float br = bih0[jj] + bhh0[jj];
        const float bz = bih0[64 + jj] + bhh0[64 + jj];
        const float bi = bih0[128 + jj];
        const float bh = bhh0[128 + jj];
        float hreg[4] = {0.f, 0.f, 0.f, 0.f};

        for (int it = 0; it < 62; ++it) {
            if (it < 60) {
                const int par = it & 1;
                const short8 ah0 = *(const short8*)&h0h[par][swzA0];
                const short8 ah1 = *(const short8*)&h0h[par][swzA1];
                const short8 al0 = *(const short8*)&h0l[par][swzA0];
                const short8 al1 = *(const short8*)&h0l[par][swzA1];
                const short8 ax  = axbuf[it * 40 + (c & 7) * 5 + q];

                f32x4 accr = {br, br, br, br};
                f32x4 accz = {bz, bz, bz, bz};
                f32x4 acci = {bi, bi, bi, bi};
                f32x4 acch = {bh, bh, bh, bh};

                accr = MFMA16(ah0, Bhh[0][0], accr); accr = MFMA16(ah1, Bhh[0][1], accr);
                accr = MFMA16(al0, Bhh[0][0], accr); accr = MFMA16(al1, Bhh[0][1], accr);
                accr = MFMA16(ah0, Bhl[0][0], accr); accr = MFMA16(ah1, Bhl[0][1], accr);
                accr = MFMA16(ax, Bc[0], accr);

                accz = MFMA16(ah0, Bhh[1][0], accz); accz = MFMA16(ah1, Bhh[1][1], accz);
                accz = MFMA16(al0, Bhh[1][0], accz); accz = MFMA16(al1, Bhh[1][1], accz);
                accz = MFMA16(ah0, Bhl[1][0], accz); accz = MFMA16(ah1, Bhl[1][1], accz);
                accz = MFMA16(ax, Bc[1], accz);

                acci = MFMA16(ax, Bc[2], acci);

                acch = MFMA16(ah0, Bhh[2][0], acch); acch = MFMA16(ah1, Bhh[2][1], acch);
                acch = MFMA16(al0, Bhh[2][0], acch); acch = MFMA16(al1, Bhh[2][1], acch);
                acch = MFMA16(ah0, Bhl[2][0], acch); acch = MFMA16(ah1, Bhl[2][1], acch);

#pragma unroll
                for (int i2 = 0; i2 < 4; ++i2) {
                    const float rr = sigm(accr[i2]);
                    const float zz = sigm(accz[i2]);
                    const float nn = tanh_(acci[i2] + rr * acch[i2]);
                    const float hv = (1.f - zz) * nn + zz * hreg[i2];
                    hreg[i2] = hv;
                    const int r  = q * 4 + i2;
                    const int ix = r * 64 + (jj ^ ((r & 7) << 3));
                    const unsigned short hi = f2bf(hv);
                    h0h[par ^ 1][ix] = hi;
                    h0l[par ^ 1][ix] = f2bf(hv - bf2f(hi));
                }
            }
            __syncthreads();
        }
    } else if (grp == 1) {
        short8 Bih[3][2], Bil[3][2];
#pragma unroll
        for (int g = 0; g < 3; ++g) {
            const int o = g * 64 + jj;
#pragma unroll
            for (int kt = 0; kt < 2; ++kt) {
                const int k0 = kt * 32 + q * 8;
#pragma unroll
                for (int e = 0; e < 8; ++e) {
                    const float v = Wih1[o * 64 + k0 + e];
                    const unsigned short hi = f2bf(v);
                    Bih[g][kt][e] = (short)hi; Bil[g][kt][e] = (short)f2bf(v - bf2f(hi));
                }
            }
        }
        const float br = bih1[jj] + bhh1[jj];
        const float bz = bih1[64 + jj] + bhh1[64 + jj];
        const float bi = bih1[128 + jj];

        for (int it = 0; it < 62; ++it) {
            if (it >= 1 && it < 61) {
                const int par = it & 1;
                const short8 gh0 = *(const short8*)&h0h[par][swzA0];
                const short8 gh1 = *(const short8*)&h0h[par][swzA1];
                const short8 gl0 = *(const short8*)&h0l[par][swzA0];
                const short8 gl1 = *(const short8*)&h0l[par][swzA1];

                f32x4 ar = {br, br, br, br};
                f32x4 az = {bz, bz, bz, bz};
                f32x4 an = {bi, bi, bi, bi};

                ar = MFMA16(gh0, Bih[0][0], ar); ar = MFMA16(gh1, Bih[0][1], ar);
                ar = MFMA16(gl0, Bih[0][0], ar); ar = MFMA16(gl1, Bih[0][1], ar);
                ar = MFMA16(gh0, Bil[0][0], ar); ar = MFMA16(gh1, Bil[0][1], ar);

                az = MFMA16(gh0, Bih[1][0], az); az = MFMA16(gh1, Bih[1][1], az);
                az = MFMA16(gl0, Bih[1][0], az); az = MFMA16(gl1, Bih[1][1], az);
                az = MFMA16(gh0, Bil[1][0], az); az = MFMA16(gh1, Bil[1][1], az);

                an = MFMA16(gh0, Bih[2][0], an); an = MFMA16(gh1, Bih[2][1], an);
                an = MFMA16(gl0, Bih[2][0], an); an = MFMA16(gl1, Bih[2][1], an);
                an = MFMA16(gh0, Bil[2][0], an); an = MFMA16(gh1, Bil[2][1], an);

#pragma unroll
                for (int i2 = 0; i2 < 4; ++i2) {
                    const int r = q * 4 + i2;
                    P1[par][r][jj]       = ar[i2];
                    P1[par][r][64 + jj]  = az[i2];
                    P1[par][r][128 + jj] = an[i2];
                }
            }
            __syncthreads();
        }
    } else {
        short8 Bhh[3][2], Bhl[3][2];
#pragma unroll
        for (int g = 0; g < 3; ++g) {
            const int o = g * 64 + jj;
#pragma unroll
            for (int kt = 0; kt < 2; ++kt) {
                const int k0 = kt * 32 + q * 8;
#pragma unroll
                for (int e = 0; e < 8; ++e) {
                    const float v = Whh1[o * 64 + k0 + e];
                    const unsigned short hi = f2bf(v);
                    Bhh[g][kt][e] = (short)hi; Bhl[g][kt][e] = (short)f2bf(v - bf2f(hi));
                }
            }
        }
        const float bh = bhh1[128 + jj];
        float hreg[4] = {0.f, 0.f, 0.f, 0.f};

        for (int it = 0; it < 62; ++it) {
            if (it >= 2) {
                const int par = it & 1;
                const short8 hh0 = *(const short8*)&h1h[par][swzA0];
                const short8 hh1_ = *(const short8*)&h1h[par][swzA1];
                const short8 hl0 = *(const short8*)&h1l[par][swzA0];
                const short8 hl1_ = *(const short8*)&h1l[par][swzA1];

                float p1r[4], p1z[4], p1n[4];
#pragma unroll
                for (int i2 = 0; i2 < 4; ++i2) {
                    const int r = q * 4 + i2;
                    p1r[i2] = P1[par ^ 1][r][jj];
                    p1z[i2] = P1[par ^ 1][r][64 + jj];
                    p1n[i2] = P1[par ^ 1][r][128 + jj];
                }

                f32x4 ar  = {p1r[0], p1r[1], p1r[2], p1r[3]};
                f32x4 az  = {p1z[0], p1z[1], p1z[2], p1z[3]};
                f32x4 ahn = {bh, bh, bh, bh};

                ar = MFMA16(hh0, Bhh[0][0], ar); ar = MFMA16(hh1_, Bhh[0][1], ar);
                ar = MFMA16(hl0, Bhh[0][0], ar); ar = MFMA16(hl1_, Bhh[0][1], ar);
                ar = MFMA16(hh0, Bhl[0][0], ar); ar = MFMA16(hh1_, Bhl[0][1], ar);

                az = MFMA16(hh0, Bhh[1][0], az); az = MFMA16(hh1_, Bhh[1][1], az);
                az = MFMA16(hl0, Bhh[1][0], az); az = MFMA16(hl1_, Bhh[1][1], az);
                az = MFMA16(hh0, Bhl[1][0], az); az = MFMA16(hh1_, Bhl[1][1], az);

                ahn = MFMA16(hh0, Bhh[2][0], ahn); ahn = MFMA16(hh1_, Bhh[2][1], ahn);
                ahn = MFMA16(hl0, Bhh[2][0], ahn); ahn = MFMA16(hl1_, Bhh[2][1], ahn);
                ahn = MFMA16(hh0, Bhl[2][0], ahn); ahn = MFMA16(hh1_, Bhl[2][1], ahn);

#pragma unroll
                for (int i2 = 0; i2 < 4; ++i2) {
                    const float rr = sigm(ar[i2]);
                    const float zz = sigm(az[i2]);
                    const float nn = tanh_(p1n[i2] + rr * ahn[i2]);
                    const float hv = (1.f - zz) * nn + zz * hreg[i2];
                    hreg[i2] = hv;
                    const int r  = q * 4 + i2;
                    const int ix = r * 64 + (jj ^ ((r & 7) << 3));
                    const unsigned short hi = f2bf(hv);
                    h1h[par ^ 1][ix] = hi;
                    h1l[par ^ 1][ix] = f2bf(hv - bf2f(hi));
                    if (it == 61 && q < 2)
                        xhid[((size_t)blockIdx.x * 8 + r) * 64 + jj] = hv;
                }
            }
            __syncthreads();
        }
    }
}

// ============================================================================
// Kernel 2: ai[n] = x_hidden[n] . W1 ; aj[n] = x_hidden[n] . W2
// ============================================================================
__global__ void aij_kernel(const float* __restrict__ xh, const float* __restrict__ W,
                           float* __restrict__ ai, float* __restrict__ aj) {
    const int n = blockIdx.x * 256 + threadIdx.x;
    const float* row = xh + (size_t)n * 64;
    float a1 = 0.f, a2 = 0.f;
#pragma unroll
    for (int k = 0; k < 64; k += 4) {
        const f32x4 v = *(const f32x4*)(row + k);
#pragma unroll
        for (int u = 0; u < 4; ++u) {
            a1 += v[u] * W[k + u];
            a2 += v[u] * W[64 + k + u];
        }
    }
    ai[n] = a1;
    aj[n] = a2;
}

// ============================================================================
// Kernel 3: finish (R9-proven phases; mask now 12-bit-per-chunk ushort).
// 256 blocks x 1024 threads, 8 rows/block.
// ============================================================================
__launch_bounds__(1024, 2)
__global__ void finish_kernel(const float* __restrict__ arw,
                              const unsigned short* __restrict__ maskw16,
                              const float* __restrict__ xh, const float* __restrict__ ai,
                              const float* __restrict__ aj, const float* __restrict__ bptr,
                              const float* __restrict__ fcw, const float* __restrict__ fcb,
                              float* __restrict__ out) {
    __shared__ __align__(16) float sc[8][2056];
    __shared__ __align__(16) float hidpart[16][8][64];
    __shared__ float redm[8][2], reds[8][2], rinv_s[8];

    const int tid = threadIdx.x;
    const int i0  = blockIdx.x * 8;

    float aiv[8];
#pragma unroll
    for (int il = 0; il < 8; ++il) aiv[il] = ai[i0 + il];
    const float bb = bptr[0];

    // ---- phase A: scores from ar + chunk mask ----
#pragma unroll
    for (int jc = 0; jc < 2; ++jc) {
        const int j = tid + jc * 1024;
        const float ajv = aj[j];
#pragma unroll
        for (int il = 0; il < 8; ++il) {
            const int p = (i0 + il) * 2048 + j;
            const float s = arw[p];
            const int cc = p / 12;
            const int g  = p - cc * 12;
            const unsigned m16 = maskw16[cc];
            float wvv = aiv[il] + ajv + s + bb;
            wvv = (wvv >= 0.f) ? wvv : 0.01f * wvv;
            sc[il][j] = ((m16 >> g) & 1u) ? wvv : 0.f;
        }
    }
    __syncthreads();

    // ---- phase B: row softmax (128 threads / row) ----
    const int row = tid >> 7;
    const int c7  = tid & 127;
    const int wh  = (tid >> 6) & 1;

    float mx = -1e30f;
#pragma unroll
    for (int m = 0; m < 16; ++m) mx = fmaxf(mx, sc[row][c7 + 128 * m]);
#pragma unroll
    for (int d = 1; d < 64; d <<= 1) mx = fmaxf(mx, __shfl_xor(mx, d, 64));
    if ((tid & 63) == 0) redm[row][wh] = mx;
    __syncthreads();
    mx = fmaxf(redm[row][0], redm[row][1]);

    float sm = 0.f;
#pragma unroll
    for (int m = 0; m < 16; ++m) {
        const int k = c7 + 128 * m;
        const float e = __expf(sc[row][k] - mx);
        sc[row][k] = e;
        sm += e;
    }
#pragma unroll
    for (int d = 1; d < 64; d <<= 1) sm += __shfl_xor(sm, d, 64);
    if ((tid & 63) == 0) reds[row][wh] = sm;
    __syncthreads();
    if ((tid & 127) == 0) rinv_s[row] = 1.f / (reds[row][0] + reds[row][1]);

    // ---- phase C: hidden = p @ x_hidden (strip-mapped) ----
    const int col   = tid & 63;
    const int strip = tid >> 6;
    const int k0s   = strip * 128;

    float acc[8] = {0.f, 0.f, 0.f, 0.f, 0.f, 0.f, 0.f, 0.f};
    for (int k = 0; k < 128; k += 4) {
        const float v0 = xh[(size_t)(k0s + k) * 64 + col];
        const float v1 = xh[(size_t)(k0s + k + 1) * 64 + col];
        const float v2 = xh[(size_t)(k0s + k + 2) * 64 + col];
        const float v3 = xh[(size_t)(k0s + k + 3) * 64 + col];
#pragma unroll
        for (int il = 0; il < 8; ++il) {
            const f32x4 e = *(const f32x4*)&sc[il][k0s + k];
            acc[il] += e[0] * v0 + e[1] * v1 + e[2] * v2 + e[3] * v3;
        }
    }
#pragma unroll
    for (int il = 0; il < 8; ++il) hidpart[strip][il][col] = acc[il];
    __syncthreads();

    // ---- phase D: reduce strips + residual + fc ----
    if (tid < 512) {
        const int r2 = tid >> 6;
        const int cl = tid & 63;
        float hsum = 0.f;
#pragma unroll
        for (int s = 0; s < 16; ++s) hsum += hidpart[s][r2][cl];
        const float h = hsum * rinv_s[r2] + xh[(size_t)(i0 + r2) * 64 + cl];
        float p = h * fcw[cl];
#pragma unroll
        for (int d = 1; d < 64; d <<= 1) p += __shfl_xor(p, d, 64);
        if (cl == 0) out[i0 + r2] = p + fcb[0];
    }
}

// ============================================================================
extern "C" void kernel_launch(void* const* d_in, const int* in_sizes, int n_in,
                              void* d_out, int out_size, void* d_ws, size_t ws_size,
                              hipStream_t stream) {
    const float* x    = (const float*)d_in[0];
    const float* rel  = (const float*)d_in[1];
    const float* Wih0 = (const float*)d_in[2];
    const float* Whh0 = (const float*)d_in[3];
    const float* bih0 = (const float*)d_in[4];
    const float* bhh0 = (const float*)d_in[5];
    const float* Wih1 = (const float*)d_in[6];
    const float* Whh1 = (const float*)d_in[7];
    const float* bih1 = (const float*)d_in[8];
    const float* bhh1 = (const float*)d_in[9];
    const float* W    = (const float*)d_in[10];
    const float* b    = (const float*)d_in[11];
    const float* fcw  = (const float*)d_in[12];
    const float* fcb  = (const float*)d_in[13];
    float* out = (float*)d_out;

    float* xh = (float*)d_ws;                      // 2048*64
    float* ai = xh + 131072;                       // 2048
    float* aj = ai + 2048;                         // 2048
    float* arw = aj + 2048;                        // 4194304 (2048x2048)
    unsigned short* maskw16 = (unsigned short*)(arw + 4194304);  // 349526 ushort

    mega_kernel<<<1024, 768, 0, stream>>>(x, Wih0, Whh0, bih0, bhh0,
                                          Wih1, Whh1, bih1, bhh1,
                                          rel, W, xh, arw, maskw16);
    aij_kernel<<<8, 256, 0, stream>>>(xh, W, ai, aj);
    finish_kernel<<<256, 1024, 0, stream>>>(arw, maskw16, xh, ai, aj, b, fcw, fcb, out);
}

// Round 13
// 176.519 us; speedup vs baseline: 1.2786x; 1.2786x over previous
//
#include <hip/hip_runtime.h>
#include <cstddef>

typedef __attribute__((ext_vector_type(8))) short short8;
typedef __attribute__((ext_vector_type(4))) float f32x4;

#define MFMA16(a, b, c) __builtin_amdgcn_mfma_f32_16x16x32_bf16((a), (b), (c), 0, 0, 0)

__device__ __forceinline__ unsigned short f2bf(float f) {
    unsigned u = __float_as_uint(f);
    u = (u + 0x7fffu + ((u >> 16) & 1u)) >> 16;
    return (unsigned short)u;
}
__device__ __forceinline__ float bf2f(unsigned short s) {
    return __uint_as_float(((unsigned)s) << 16);
}
__device__ __forceinline__ float sigm(float v) { return 1.f / (1.f + __expf(-v)); }
__device__ __forceinline__ float tanh_(float v) {
    float a = fabsf(v);
    float e = __expf(-2.f * a);
    float t = (1.f - e) / (1.f + e);
    return v < 0.f ? -t : t;
}

// Compiler-level ordering fence: per-thread alias analysis cannot see that
// other lanes fill the LDS gaps, so it may hoist ds_reads above the same
// iteration's ds_writes (R6 tripwire / R7 accuracy failure). Pin program
// order; the DS pipeline is in-order per wave, so program order is enough.
__device__ __forceinline__ void lds_order_fence() {
    asm volatile("" ::: "memory");
    __builtin_amdgcn_sched_barrier(0);
}

// ============================================================================
// Kernel 1: fused 2-layer GRU, layer-pipelined wave groups (R3, proven 4x).
// ============================================================================
__launch_bounds__(768, 3)
__global__ void gru_kernel(const float* __restrict__ x,
                           const float* __restrict__ Wih0, const float* __restrict__ Whh0,
                           const float* __restrict__ bih0, const float* __restrict__ bhh0,
                           const float* __restrict__ Wih1, const float* __restrict__ Whh1,
                           const float* __restrict__ bih1, const float* __restrict__ bhh1,
                           float* __restrict__ xhid) {
    __shared__ __align__(16) unsigned short h0h[2][1024], h0l[2][1024];
    __shared__ __align__(16) unsigned short h1h[2][1024], h1l[2][1024];
    __shared__ __align__(16) float P1[2][16][195];
    __shared__ __align__(16) short8 axbuf[2400];

    const int tid  = threadIdx.x;
    const int grp  = tid >> 8;
    const int lane = tid & 63;
    const int gw   = (tid >> 6) & 3;
    const int c    = lane & 15;
    const int q    = lane >> 4;
    const int jj   = gw * 16 + c;

    for (int i = tid; i < 1024; i += 768) {
        h0h[0][i] = 0; h0l[0][i] = 0; h1h[0][i] = 0; h1l[0][i] = 0;
    }
    {
        const float* xb = x + (size_t)blockIdx.x * 8 * 360;
        for (int f = tid; f < 1920; f += 768) {
            const int t = f >> 5, s = (f >> 2) & 7, qq = f & 3;
            unsigned short Hh[6], Ll[6];
#pragma unroll
            for (int d = 0; d < 6; ++d) {
                const float v = xb[s * 360 + d * 60 + t];
                Hh[d] = f2bf(v); Ll[d] = f2bf(v - bf2f(Hh[d]));
            }
            short8 fr;
#pragma unroll
            for (int e = 0; e < 8; ++e) {
                const int k = qq * 8 + e;
                unsigned short u = 0;
                if (k < 6) u = Hh[k];
                else if (k < 12) u = Ll[k - 6];
                else if (k < 18) u = Hh[k - 12];
                fr[e] = (short)u;
            }
            axbuf[t * 40 + s * 5 + qq] = fr;
        }
    }

    const int ka    = q * 8;
    const int swzA0 = c * 64 + (ka ^ ((c & 7) << 3));
    const int swzA1 = c * 64 + ((32 + ka) ^ ((c & 7) << 3));

    __syncthreads();

    if (grp == 0) {
        short8 Bhh[3][2], Bhl[3][2], Bc[3];
#pragma unroll
        for (int g = 0; g < 3; ++g) {
            const int o = g * 64 + jj;
#pragma unroll
            for (int kt = 0; kt < 2; ++kt) {
                const int k0 = kt * 32 + q * 8;
#pragma unroll
                for (int e = 0; e < 8; ++e) {
                    const float v = Whh0[o * 64 + k0 + e];
                    const unsigned short hi = f2bf(v);
                    Bhh[g][kt][e] = (short)hi; Bhl[g][kt][e] = (short)f2bf(v - bf2f(hi));
                }
            }
#pragma unroll
            for (int e = 0; e < 8; ++e) {
                const int ks = q * 8 + e;
                unsigned short bv = 0;
                if (ks < 6)       bv = f2bf(Wih0[o * 6 + ks]);
                else if (ks < 12) bv = f2bf(Wih0[o * 6 + ks - 6]);
                else if (ks < 18) {
                    const float v = Wih0[o * 6 + ks - 12];
                    const unsigned short hi = f2bf(v);
                    bv = f2bf(v - bf2f(hi));
                }
                Bc[g][e] = (short)bv;
            }
        }
        const float br = bih0[jj] + bhh0[jj];
        const float bz = bih0[64 + jj] + bhh0[64 + jj];
        const float bi = bih0[128 + jj];
        const float bh = bhh0[128 + jj];
        float hreg[4] = {0.f, 0.f, 0.f, 0.f};

        for (int it = 0; it < 62; ++it) {
            if (it < 60) {
                const int par = it & 1;
                const short8 ah0 = *(const short8*)&h0h[par][swzA0];
                const short8 ah1 = *(const short8*)&h0h[par][swzA1];
                const short8 al0 = *(const short8*)&h0l[par][swzA0];
                const short8 al1 = *(const short8*)&h0l[par][swzA1];
                const short8 ax  = axbuf[it * 40 + (c & 7) * 5 + q];

                f32x4 accr = {br, br, br, br};
                f32x4 accz = {bz, bz, bz, bz};
                f32x4 acci = {bi, bi, bi, bi};
                f32x4 acch = {bh, bh, bh, bh};

                accr = MFMA16(ah0, Bhh[0][0], accr); accr = MFMA16(ah1, Bhh[0][1], accr);
                accr = MFMA16(al0, Bhh[0][0], accr); accr = MFMA16(al1, Bhh[0][1], accr);
                accr = MFMA16(ah0, Bhl[0][0], accr); accr = MFMA16(ah1, Bhl[0][1], accr);
                accr = MFMA16(ax, Bc[0], accr);

                accz = MFMA16(ah0, Bhh[1][0], accz); accz = MFMA16(ah1, Bhh[1][1], accz);
                accz = MFMA16(al0, Bhh[1][0], accz); accz = MFMA16(al1, Bhh[1][1], accz);
                accz = MFMA16(ah0, Bhl[1][0], accz); accz = MFMA16(ah1, Bhl[1][1], accz);
                accz = MFMA16(ax, Bc[1], accz);

                acci = MFMA16(ax, Bc[2], acci);

                acch = MFMA16(ah0, Bhh[2][0], acch); acch = MFMA16(ah1, Bhh[2][1], acch);
                acch = MFMA16(al0, Bhh[2][0], acch); acch = MFMA16(al1, Bhh[2][1], acch);
                acch = MFMA16(ah0, Bhl[2][0], acch); acch = MFMA16(ah1, Bhl[2][1], acch);

#pragma unroll
                for (int i2 = 0; i2 < 4; ++i2) {
                    const float rr = sigm(accr[i2]);
                    const float zz = sigm(accz[i2]);
                    const float nn = tanh_(acci[i2] + rr * acch[i2]);
                    const float hv = (1.f - zz) * nn + zz * hreg[i2];
                    hreg[i2] = hv;
                    const int r  = q * 4 + i2;
                    const int ix = r * 64 + (jj ^ ((r & 7) << 3));
                    const unsigned short hi = f2bf(hv);
                    h0h[par ^ 1][ix] = hi;
                    h0l[par ^ 1][ix] = f2bf(hv - bf2f(hi));
                }
            }
            __syncthreads();
        }
    } else if (grp == 1) {
        short8 Bih[3][2], Bil[3][2];
#pragma unroll
        for (int g = 0; g < 3; ++g) {
            const int o = g * 64 + jj;
#pragma unroll
            for (int kt = 0; kt < 2; ++kt) {
                const int k0 = kt * 32 + q * 8;
#pragma unroll
                for (int e = 0; e < 8; ++e) {
                    const float v = Wih1[o * 64 + k0 + e];
                    const unsigned short hi = f2bf(v);
                    Bih[g][kt][e] = (short)hi; Bil[g][kt][e] = (short)f2bf(v - bf2f(hi));
                }
            }
        }
        const float br = bih1[jj] + bhh1[jj];
        const float bz = bih1[64 + jj] + bhh1[64 + jj];
        const float bi = bih1[128 + jj];

        for (int it = 0; it < 62; ++it) {
            if (it >= 1 && it < 61) {
                const int par = it & 1;
                const short8 gh0 = *(const short8*)&h0h[par][swzA0];
                const short8 gh1 = *(const short8*)&h0h[par][swzA1];
                const short8 gl0 = *(const short8*)&h0l[par][swzA0];
                const short8 gl1 = *(const short8*)&h0l[par][swzA1];

                f32x4 ar = {br, br, br, br};
                f32x4 az = {bz, bz, bz, bz};
                f32x4 an = {bi, bi, bi, bi};

                ar = MFMA16(gh0, Bih[0][0], ar); ar = MFMA16(gh1, Bih[0][1], ar);
                ar = MFMA16(gl0, Bih[0][0], ar); ar = MFMA16(gl1, Bih[0][1], ar);
                ar = MFMA16(gh0, Bil[0][0], ar); ar = MFMA16(gh1, Bil[0][1], ar);

                az = MFMA16(gh0, Bih[1][0], az); az = MFMA16(gh1, Bih[1][1], az);
                az = MFMA16(gl0, Bih[1][0], az); az = MFMA16(gl1, Bih[1][1], az);
                az = MFMA16(gh0, Bil[1][0], az); az = MFMA16(gh1, Bil[1][1], az);

                an = MFMA16(gh0, Bih[2][0], an); an = MFMA16(gh1, Bih[2][1], an);
                an = MFMA16(gl0, Bih[2][0], an); an = MFMA16(gl1, Bih[2][1], an);
                an = MFMA16(gh0, Bil[2][0], an); an = MFMA16(gh1, Bil[2][1], an);

#pragma unroll
                for (int i2 = 0; i2 < 4; ++i2) {
                    const int r = q * 4 + i2;
                    P1[par][r][jj]       = ar[i2];
                    P1[par][r][64 + jj]  = az[i2];
                    P1[par][r][128 + jj] = an[i2];
                }
            }
            __syncthreads();
        }
    } else {
        short8 Bhh[3][2], Bhl[3][2];
#pragma unroll
        for (int g = 0; g < 3; ++g) {
            const int o = g * 64 + jj;
#pragma unroll
            for (int kt = 0; kt < 2; ++kt) {
                const int k0 = kt * 32 + q * 8;
#pragma unroll
                for (int e = 0; e < 8; ++e) {
                    const float v = Whh1[o * 64 + k0 + e];
                    const unsigned short hi = f2bf(v);
                    Bhh[g][kt][e] = (short)hi; Bhl[g][kt][e] = (short)f2bf(v - bf2f(hi));
                }
            }
        }
        const float bh = bhh1[128 + jj];
        float hreg[4] = {0.f, 0.f, 0.f, 0.f};

        for (int it = 0; it < 62; ++it) {
            if (it >= 2) {
                const int par = it & 1;
                const short8 hh0 = *(const short8*)&h1h[par][swzA0];
                const short8 hh1_ = *(const short8*)&h1h[par][swzA1];
                const short8 hl0 = *(const short8*)&h1l[par][swzA0];
                const short8 hl1_ = *(const short8*)&h1l[par][swzA1];

                float p1r[4], p1z[4], p1n[4];
#pragma unroll
                for (int i2 = 0; i2 < 4; ++i2) {
                    const int r = q * 4 + i2;
                    p1r[i2] = P1[par ^ 1][r][jj];
                    p1z[i2] = P1[par ^ 1][r][64 + jj];
                    p1n[i2] = P1[par ^ 1][r][128 + jj];
                }

                f32x4 ar  = {p1r[0], p1r[1], p1r[2], p1r[3]};
                f32x4 az  = {p1z[0], p1z[1], p1z[2], p1z[3]};
                f32x4 ahn = {bh, bh, bh, bh};

                ar = MFMA16(hh0, Bhh[0][0], ar); ar = MFMA16(hh1_, Bhh[0][1], ar);
                ar = MFMA16(hl0, Bhh[0][0], ar); ar = MFMA16(hl1_, Bhh[0][1], ar);
                ar = MFMA16(hh0, Bhl[0][0], ar); ar = MFMA16(hh1_, Bhl[0][1], ar);

                az = MFMA16(hh0, Bhh[1][0], az); az = MFMA16(hh1_, Bhh[1][1], az);
                az = MFMA16(hl0, Bhh[1][0], az); az = MFMA16(hl1_, Bhh[1][1], az);
                az = MFMA16(hh0, Bhl[1][0], az); az = MFMA16(hh1_, Bhl[1][1], az);

                ahn = MFMA16(hh0, Bhh[2][0], ahn); ahn = MFMA16(hh1_, Bhh[2][1], ahn);
                ahn = MFMA16(hl0, Bhh[2][0], ahn); ahn = MFMA16(hl1_, Bhh[2][1], ahn);
                ahn = MFMA16(hh0, Bhl[2][0], ahn); ahn = MFMA16(hh1_, Bhl[2][1], ahn);

#pragma unroll
                for (int i2 = 0; i2 < 4; ++i2) {
                    const float rr = sigm(ar[i2]);
                    const float zz = sigm(az[i2]);
                    const float nn = tanh_(p1n[i2] + rr * ahn[i2]);
                    const float hv = (1.f - zz) * nn + zz * hreg[i2];
                    hreg[i2] = hv;
                    const int r  = q * 4 + i2;
                    const int ix = r * 64 + (jj ^ ((r & 7) << 3));
                    const unsigned short hi = f2bf(hv);
                    h1h[par ^ 1][ix] = hi;
                    h1l[par ^ 1][ix] = f2bf(hv - bf2f(hi));
                    if (it == 61 && q < 2)
                        xhid[((size_t)blockIdx.x * 8 + r) * 64 + jj] = hv;
                }
            }
            __syncthreads();
        }
    }
}

// ============================================================================
// Kernel 2: ai[n] = x_hidden[n] . W1 ; aj[n] = x_hidden[n] . W2
// ============================================================================
__global__ void aij_kernel(const float* __restrict__ xh, const float* __restrict__ W,
                           float* __restrict__ ai, float* __restrict__ aj) {
    const int n = blockIdx.x * 256 + threadIdx.x;
    const float* row = xh + (size_t)n * 64;
    float a1 = 0.f, a2 = 0.f;
#pragma unroll
    for (int k = 0; k < 64; k += 4) {
        const f32x4 v = *(const f32x4*)(row + k);
#pragma unroll
        for (int u = 0; u < 4; ++u) {
            a1 += v[u] * W[k + u];
            a2 += v[u] * W[64 + k + u];
        }
    }
    ai[n] = a1;
    aj[n] = a2;
}

// ============================================================================
// Kernel 3: relfused (R8 verbatim — best passing state, 177.7 us total).
// 256 blocks x 1024 threads (1 block/CU), 8 rows/block.
// Phase A: 16 waves free-running, each streams 16 dense 5KB tasks with
// register double-buffering; intra-wave LDS transpose in a private 5KB
// scratch. lds_order_fence() around the transpose reads pins write->read
// program order. Phase A runs at the ~3 TB/s read-path rate measured across
// five independent streamer structures this session.
// ============================================================================
__launch_bounds__(1024, 2)
__global__ void relfused_kernel(const float* __restrict__ rel, const float* __restrict__ xh,
                                const float* __restrict__ ai, const float* __restrict__ aj,
                                const float* __restrict__ W, const float* __restrict__ bptr,
                                const float* __restrict__ fcw, const float* __restrict__ fcb,
                                float* __restrict__ out) {
    __shared__ __align__(16) float sc[8][2056];
    __shared__ __align__(16) float scratch[16][1280];   // phase A; reused as hidpart in C
    __shared__ float redm[8][2], reds[8][2], rinv_s[8];

    const int tid  = threadIdx.x;
    const int lane = tid & 63;
    const int wvA  = tid >> 6;        // wave 0..15
    const int i0   = blockIdx.x * 8;

    float w3[20];
#pragma unroll
    for (int e = 0; e < 20; ++e) w3[e] = W[128 + e];
    const float bb = bptr[0];
    float* b = scratch[wvA];

    // ---------------- phase A: free-running per-wave streaming ----------------
    f32x4 A0, A1, A2, A3, A4, B0, B1, B2, B3, B4;

#define REL_ISSUE(tk, R0, R1, R2, R3, R4)                                        \
    {                                                                            \
        const int task_ = wvA * 16 + (tk);                                       \
        const int il_ = task_ >> 5, ch_ = task_ & 31;                            \
        const float* gp = rel + ((size_t)(i0 + il_) * 2048 + ch_ * 64) * 20      \
                          + lane * 4;                                            \
        R0 = *(const f32x4*)(gp);                                                \
        R1 = *(const f32x4*)(gp + 256);                                          \
        R2 = *(const f32x4*)(gp + 512);                                          \
        R3 = *(const f32x4*)(gp + 768);                                          \
        R4 = *(const f32x4*)(gp + 1024);                                         \
    }

#define REL_CONSUME(tk, R0, R1, R2, R3, R4)                                      \
    {                                                                            \
        const int task_ = wvA * 16 + (tk);                                       \
        const int il_ = task_ >> 5, ch_ = task_ & 31;                            \
        *(f32x4*)&b[0    + lane * 4] = R0;                                       \
        *(f32x4*)&b[256  + lane * 4] = R1;                                       \
        *(f32x4*)&b[512  + lane * 4] = R2;                                       \
        *(f32x4*)&b[768  + lane * 4] = R3;                                       \
        *(f32x4*)&b[1024 + lane * 4] = R4;                                       \
        lds_order_fence();   /* writes BEFORE reads — pin order */               \
        float arv = 0.f, ms = 0.f;                                               \
        _Pragma("unroll")                                                        \
        for (int e = 0; e < 5; ++e) {                                            \
            const f32x4 v = *(const f32x4*)&b[lane * 20 + e * 4];                \
            arv += v[0] * w3[e * 4] + v[1] * w3[e * 4 + 1]                       \
                 + v[2] * w3[e * 4 + 2] + v[3] * w3[e * 4 + 3];                  \
            ms  += v[0] + v[1] + v[2] + v[3];                                    \
        }                                                                        \
        lds_order_fence();   /* reads BEFORE next iteration's writes */          \
        const int j_ = ch_ * 64 + lane;                                          \
        float wvv = ai[i0 + il_] + aj[j_] + arv + bb;                            \
        wvv = (wvv >= 0.f) ? wvv : 0.01f * wvv;                                  \
        sc[il_][j_] = (ms != 0.f) ? wvv : 0.f;                                   \
    }

    REL_ISSUE(0, A0, A1, A2, A3, A4);
    for (int t = 0; t < 16; ++t) {
        if ((t & 1) == 0) {
            if (t < 15) REL_ISSUE(t + 1, B0, B1, B2, B3, B4);
            REL_CONSUME(t, A0, A1, A2, A3, A4);
        } else {
            if (t < 15) REL_ISSUE(t + 1, A0, A1, A2, A3, A4);
            REL_CONSUME(t, B0, B1, B2, B3, B4);
        }
    }
    __syncthreads();

    // ---------------- phase B: row softmax (128 threads / row) ----------------
    const int row = tid >> 7;
    const int c7  = tid & 127;
    const int wh  = (tid >> 6) & 1;

    float mx = -1e30f;
#pragma unroll
    for (int m = 0; m < 16; ++m) mx = fmaxf(mx, sc[row][c7 + 128 * m]);
#pragma unroll
    for (int d = 1; d < 64; d <<= 1) mx = fmaxf(mx, __shfl_xor(mx, d, 64));
    if ((tid & 63) == 0) redm[row][wh] = mx;
    __syncthreads();
    mx = fmaxf(redm[row][0], redm[row][1]);

    float sm = 0.f;
#pragma unroll
    for (int m = 0; m < 16; ++m) {
        const int k = c7 + 128 * m;
        const float e = __expf(sc[row][k] - mx);
        sc[row][k] = e;
        sm += e;
    }
#pragma unroll
    for (int d = 1; d < 64; d <<= 1) sm += __shfl_xor(sm, d, 64);
    if ((tid & 63) == 0) reds[row][wh] = sm;
    __syncthreads();
    if ((tid & 127) == 0) rinv_s[row] = 1.f / (reds[row][0] + reds[row][1]);

    // ---------------- phase C: hidden = p @ x_hidden (strip-mapped) -----------
    float (*hidpart)[8][64] = (float (*)[8][64])scratch;   // scratch is dead now
    const int col   = tid & 63;
    const int strip = tid >> 6;
    const int k0s   = strip * 128;

    float acc[8] = {0.f, 0.f, 0.f, 0.f, 0.f, 0.f, 0.f, 0.f};
    for (int k = 0; k < 128; k += 4) {
        const float v0 = xh[(size_t)(k0s + k) * 64 + col];
        const float v1 = xh[(size_t)(k0s + k + 1) * 64 + col];
        const float v2 = xh[(size_t)(k0s + k + 2) * 64 + col];
        const float v3 = xh[(size_t)(k0s + k + 3) * 64 + col];
#pragma unroll
        for (int il = 0; il < 8; ++il) {
            const f32x4 e = *(const f32x4*)&sc[il][k0s + k];
            acc[il] += e[0] * v0 + e[1] * v1 + e[2] * v2 + e[3] * v3;
        }
    }
#pragma unroll
    for (int il = 0; il < 8; ++il) hidpart[strip][il][col] = acc[il];
    __syncthreads();

    // ---------------- phase D: reduce strips + residual + fc ----------------
    if (tid < 512) {
        const int r2 = tid >> 6;
        const int cl = tid & 63;
        float hsum = 0.f;
#pragma unroll
        for (int s = 0; s < 16; ++s) hsum += hidpart[s][r2][cl];
        const float h = hsum * rinv_s[r2] + xh[(size_t)(i0 + r2) * 64 + cl];
        float p = h * fcw[cl];
#pragma unroll
        for (int d = 1; d < 64; d <<= 1) p += __shfl_xor(p, d, 64);
        if (cl == 0) out[i0 + r2] = p + fcb[0];
    }
}

// ============================================================================
extern "C" void kernel_launch(void* const* d_in, const int* in_sizes, int n_in,
                              void* d_out, int out_size, void* d_ws, size_t ws_size,
                              hipStream_t stream) {
    const float* x    = (const float*)d_in[0];
    const float* rel  = (const float*)d_in[1];
    const float* Wih0 = (const float*)d_in[2];
    const float* Whh0 = (const float*)d_in[3];
    const float* bih0 = (const float*)d_in[4];
    const float* bhh0 = (const float*)d_in[5];
    const float* Wih1 = (const float*)d_in[6];
    const float* Whh1 = (const float*)d_in[7];
    const float* bih1 = (const float*)d_in[8];
    const float* bhh1 = (const float*)d_in[9];
    const float* W    = (const float*)d_in[10];
    const float* b    = (const float*)d_in[11];
    const float* fcw  = (const float*)d_in[12];
    const float* fcb  = (const float*)d_in[13];
    float* out = (float*)d_out;

    float* xh = (float*)d_ws;          // 2048*64 fp32
    float* ai = xh + 2048 * 64;        // 2048
    float* aj = ai + 2048;             // 2048

    gru_kernel<<<256, 768, 0, stream>>>(x, Wih0, Whh0, bih0, bhh0,
                                        Wih1, Whh1, bih1, bhh1, xh);
    aij_kernel<<<8, 256, 0, stream>>>(xh, W, ai, aj);
    relfused_kernel<<<256, 1024, 0, stream>>>(rel, xh, ai, aj, W, b, fcw, fcb, out);
}